// Round 3
// baseline (46.489 us; speedup 1.0000x reference)
//
#include <hip/hip_runtime.h>

// Problem constants (match reference)
#define BB 128
#define CC 5
#define HH 128
#define WW 128
#define HWSZ (HH * WW)              // 16384
#define NCELLS (BB * HH * WW)       // 2,097,152
#define N4 (NCELLS / 4)             // 524,288 float4 cell-groups (= 2048 blocks * 256 threads exactly)

// ext_vector type so inline-asm "v" constraints lower to a VGPR quad
typedef float vfloat4 __attribute__((ext_vector_type(4)));

__device__ __forceinline__ vfloat4 ld4(const float* p) {
    return *reinterpret_cast<const vfloat4*>(p);
}

__global__ __launch_bounds__(256) void yolo_loss_kernel(
    const float* __restrict__ labela,
    const float* __restrict__ labelb,
    const float* __restrict__ pred_ab,
    const float* __restrict__ pred_ba,
    float* __restrict__ out)
{
    const int i  = blockIdx.x * blockDim.x + threadIdx.x;  // float4-group index (grid exact)
    const int cb = i * 4;                                  // base cell index (b*HW + hw)
    const int b  = cb >> 14;                               // / 16384
    const int hw = cb & (HWSZ - 1);
    const size_t base = (size_t)b * (CC * HWSZ) + hw;      // channel-0 offset

    // ---- load phase: 20 independent float4 loads ----
    vfloat4 la0 = ld4(labela  + base + 0 * HWSZ);
    vfloat4 la1 = ld4(labela  + base + 1 * HWSZ);
    vfloat4 la2 = ld4(labela  + base + 2 * HWSZ);
    vfloat4 la3 = ld4(labela  + base + 3 * HWSZ);
    vfloat4 la4 = ld4(labela  + base + 4 * HWSZ);
    vfloat4 pa0 = ld4(pred_ab + base + 0 * HWSZ);
    vfloat4 pa1 = ld4(pred_ab + base + 1 * HWSZ);
    vfloat4 pa2 = ld4(pred_ab + base + 2 * HWSZ);
    vfloat4 pa3 = ld4(pred_ab + base + 3 * HWSZ);
    vfloat4 pa4 = ld4(pred_ab + base + 4 * HWSZ);
    vfloat4 lb0 = ld4(labelb  + base + 0 * HWSZ);
    vfloat4 lb1 = ld4(labelb  + base + 1 * HWSZ);
    vfloat4 lb2 = ld4(labelb  + base + 2 * HWSZ);
    vfloat4 lb3 = ld4(labelb  + base + 3 * HWSZ);
    vfloat4 lb4 = ld4(labelb  + base + 4 * HWSZ);
    vfloat4 pb0 = ld4(pred_ba + base + 0 * HWSZ);
    vfloat4 pb1 = ld4(pred_ba + base + 1 * HWSZ);
    vfloat4 pb2 = ld4(pred_ba + base + 2 * HWSZ);
    vfloat4 pb3 = ld4(pred_ba + base + 3 * HWSZ);
    vfloat4 pb4 = ld4(pred_ba + base + 4 * HWSZ);

    // Pin ALL 20 results in one volatile asm: loads cannot sink below it,
    // dependent compute cannot hoist above it -> backend emits one 20-load
    // clause (max MLP per wave, single vmcnt stall).
    asm volatile("" ::
        "v"(la0), "v"(la1), "v"(la2), "v"(la3), "v"(la4),
        "v"(pa0), "v"(pa1), "v"(pa2), "v"(pa3), "v"(pa4),
        "v"(lb0), "v"(lb1), "v"(lb2), "v"(lb3), "v"(lb4),
        "v"(pb0), "v"(pb1), "v"(pb2), "v"(pb3), "v"(pb4));

    // ---- compute phase ----
    float sx = 0.f, sy = 0.f, sz = 0.f, sw = 0.f;
    float d;
    d = la0.x - pa0.x; sx += d * d;  d = lb0.x - pb0.x; sx += d * d;
    d = la0.y - pa0.y; sy += d * d;  d = lb0.y - pb0.y; sy += d * d;
    d = la0.z - pa0.z; sz += d * d;  d = lb0.z - pb0.z; sz += d * d;
    d = la0.w - pa0.w; sw += d * d;  d = lb0.w - pb0.w; sw += d * d;

    d = la1.x - pa1.x; sx += d * d;  d = lb1.x - pb1.x; sx += d * d;
    d = la1.y - pa1.y; sy += d * d;  d = lb1.y - pb1.y; sy += d * d;
    d = la1.z - pa1.z; sz += d * d;  d = lb1.z - pb1.z; sz += d * d;
    d = la1.w - pa1.w; sw += d * d;  d = lb1.w - pb1.w; sw += d * d;

    d = la2.x - pa2.x; sx += d * d;  d = lb2.x - pb2.x; sx += d * d;
    d = la2.y - pa2.y; sy += d * d;  d = lb2.y - pb2.y; sy += d * d;
    d = la2.z - pa2.z; sz += d * d;  d = lb2.z - pb2.z; sz += d * d;
    d = la2.w - pa2.w; sw += d * d;  d = lb2.w - pb2.w; sw += d * d;

    d = la3.x - pa3.x; sx += d * d;  d = lb3.x - pb3.x; sx += d * d;
    d = la3.y - pa3.y; sy += d * d;  d = lb3.y - pb3.y; sy += d * d;
    d = la3.z - pa3.z; sz += d * d;  d = lb3.z - pb3.z; sz += d * d;
    d = la3.w - pa3.w; sw += d * d;  d = lb3.w - pb3.w; sw += d * d;

    d = la4.x - pa4.x; sx += d * d;  d = lb4.x - pb4.x; sx += d * d;
    d = la4.y - pa4.y; sy += d * d;  d = lb4.y - pb4.y; sy += d * d;
    d = la4.z - pa4.z; sz += d * d;  d = lb4.z - pb4.z; sz += d * d;
    d = la4.w - pa4.w; sw += d * d;  d = lb4.w - pb4.w; sw += d * d;

    // la0 is the objectness mask channel
    float cell = (la0.x != 0.f ? sx : 0.f)
               + (la0.y != 0.f ? sy : 0.f)
               + (la0.z != 0.f ? sz : 0.f)
               + (la0.w != 0.f ? sw : 0.f);

    // ---- wave(64) shuffle reduction ----
    #pragma unroll
    for (int off = 32; off > 0; off >>= 1)
        cell += __shfl_down(cell, off, 64);

    __shared__ float wsum[4];                 // 256 threads = 4 waves
    const int lane = threadIdx.x & 63;
    const int wid  = threadIdx.x >> 6;
    if (lane == 0) wsum[wid] = cell;
    __syncthreads();
    if (threadIdx.x == 0) {
        const float t = wsum[0] + wsum[1] + wsum[2] + wsum[3];
        atomicAdd(out, t);
    }
}

extern "C" void kernel_launch(void* const* d_in, const int* in_sizes, int n_in,
                              void* d_out, int out_size, void* d_ws, size_t ws_size,
                              hipStream_t stream) {
    const float* labela  = (const float*)d_in[0];
    const float* labelb  = (const float*)d_in[1];
    const float* pred_ab = (const float*)d_in[2];
    const float* pred_ba = (const float*)d_in[3];
    float* out = (float*)d_out;

    // d_out is poisoned once before timing and never re-poisoned between
    // replays: zero it ourselves every launch (graph-capture safe).
    hipMemsetAsync(out, 0, sizeof(float), stream);

    const int threads = 256;
    const int blocks  = N4 / threads;                      // 2048, exact
    yolo_loss_kernel<<<blocks, threads, 0, stream>>>(labela, labelb, pred_ab, pred_ba, out);
}

// Round 4
// 31.377 us; speedup vs baseline: 1.4816x; 1.4816x over previous
//
#include <hip/hip_runtime.h>

// Problem constants (match reference)
#define BB 128
#define CC 5
#define HH 128
#define WW 128
#define HWSZ (HH * WW)              // 16384
#define NCELLS (BB * HH * WW)       // 2,097,152
#define N4 (NCELLS / 4)             // 524,288 float4 cell-groups
#define NBLOCKS (N4 / 256)          // 2048 blocks, exact

__device__ __forceinline__ float4 ld4(const float* p) {
    return *reinterpret_cast<const float4*>(p);
}

// Kernel 1: per-block masked SSE partial sums -> ws[blockIdx.x] (plain store,
// no atomics, no cross-XCD serialization).
__global__ __launch_bounds__(256) void yolo_partial_kernel(
    const float* __restrict__ labela,
    const float* __restrict__ labelb,
    const float* __restrict__ pred_ab,
    const float* __restrict__ pred_ba,
    float* __restrict__ ws)
{
    const int i  = blockIdx.x * blockDim.x + threadIdx.x;  // float4-group index (grid exact)
    const int cb = i * 4;                                  // base cell index (b*HW + hw)
    const int b  = cb >> 14;                               // / 16384
    const int hw = cb & (HWSZ - 1);
    const size_t base = (size_t)b * (CC * HWSZ) + hw;      // channel-0 offset

    float4 la[CC], pa[CC], lb[CC], pb[CC];
    #pragma unroll
    for (int c = 0; c < CC; ++c) la[c] = ld4(labela  + base + (size_t)c * HWSZ);
    #pragma unroll
    for (int c = 0; c < CC; ++c) pa[c] = ld4(pred_ab + base + (size_t)c * HWSZ);
    #pragma unroll
    for (int c = 0; c < CC; ++c) lb[c] = ld4(labelb  + base + (size_t)c * HWSZ);
    #pragma unroll
    for (int c = 0; c < CC; ++c) pb[c] = ld4(pred_ba + base + (size_t)c * HWSZ);

    float sx = 0.f, sy = 0.f, sz = 0.f, sw = 0.f;
    #pragma unroll
    for (int c = 0; c < CC; ++c) {
        float d;
        d = la[c].x - pa[c].x; sx += d * d;  d = lb[c].x - pb[c].x; sx += d * d;
        d = la[c].y - pa[c].y; sy += d * d;  d = lb[c].y - pb[c].y; sy += d * d;
        d = la[c].z - pa[c].z; sz += d * d;  d = lb[c].z - pb[c].z; sz += d * d;
        d = la[c].w - pa[c].w; sw += d * d;  d = lb[c].w - pb[c].w; sw += d * d;
    }
    float cell = (la[0].x != 0.f ? sx : 0.f)
               + (la[0].y != 0.f ? sy : 0.f)
               + (la[0].z != 0.f ? sz : 0.f)
               + (la[0].w != 0.f ? sw : 0.f);

    // wave(64) shuffle reduction
    #pragma unroll
    for (int off = 32; off > 0; off >>= 1)
        cell += __shfl_down(cell, off, 64);

    __shared__ float wsum[4];                 // 256 threads = 4 waves
    const int lane = threadIdx.x & 63;
    const int wid  = threadIdx.x >> 6;
    if (lane == 0) wsum[wid] = cell;
    __syncthreads();
    if (threadIdx.x == 0)
        ws[blockIdx.x] = wsum[0] + wsum[1] + wsum[2] + wsum[3];
}

// Kernel 2: reduce the 2048 partials -> out[0] (plain store; overwrites the
// harness's poison every call, so no memset is needed).
__global__ __launch_bounds__(256) void yolo_final_kernel(
    const float* __restrict__ ws,
    float* __restrict__ out)
{
    float s = 0.f;
    #pragma unroll
    for (int k = 0; k < NBLOCKS / 256; ++k)            // 8 strided loads/thread
        s += ws[threadIdx.x + k * 256];

    #pragma unroll
    for (int off = 32; off > 0; off >>= 1)
        s += __shfl_down(s, off, 64);

    __shared__ float wsum[4];
    const int lane = threadIdx.x & 63;
    const int wid  = threadIdx.x >> 6;
    if (lane == 0) wsum[wid] = s;
    __syncthreads();
    if (threadIdx.x == 0)
        out[0] = wsum[0] + wsum[1] + wsum[2] + wsum[3];
}

extern "C" void kernel_launch(void* const* d_in, const int* in_sizes, int n_in,
                              void* d_out, int out_size, void* d_ws, size_t ws_size,
                              hipStream_t stream) {
    const float* labela  = (const float*)d_in[0];
    const float* labelb  = (const float*)d_in[1];
    const float* pred_ab = (const float*)d_in[2];
    const float* pred_ba = (const float*)d_in[3];
    float* ws  = (float*)d_ws;    // 2048 floats = 8 KB of scratch
    float* out = (float*)d_out;

    yolo_partial_kernel<<<NBLOCKS, 256, 0, stream>>>(labela, labelb, pred_ab, pred_ba, ws);
    yolo_final_kernel<<<1, 256, 0, stream>>>(ws, out);
}

// Round 5
// 30.527 us; speedup vs baseline: 1.5229x; 1.0278x over previous
//
#include <hip/hip_runtime.h>

// Problem constants (match reference)
#define BB 128
#define CC 5
#define HH 128
#define WW 128
#define HWSZ (HH * WW)              // 16384
#define NCELLS (BB * HH * WW)       // 2,097,152
#define N4 (NCELLS / 4)             // 524,288 float4 cell-groups
#define NBLOCKS (N4 / 256)          // 2048 blocks, exact

__device__ __forceinline__ float4 ld4(const float* p) {
    return *reinterpret_cast<const float4*>(p);
}

// Kernel 1: per-block masked SSE partial sums -> ws[blockIdx.x].
// Mask-skip: a thread whose 4 objectness cells are all zero contributes 0
// and skips its remaining 19 float4 loads — at 10% object rate this kills
// ~66% of lane requests and ~18.5% of 64B line fetches (fully-dead lines).
__global__ __launch_bounds__(256) void yolo_partial_kernel(
    const float* __restrict__ labela,
    const float* __restrict__ labelb,
    const float* __restrict__ pred_ab,
    const float* __restrict__ pred_ba,
    float* __restrict__ ws)
{
    const int i  = blockIdx.x * blockDim.x + threadIdx.x;  // float4-group index (grid exact)
    const int cb = i * 4;                                  // base cell index (b*HW + hw)
    const int b  = cb >> 14;                               // / 16384
    const int hw = cb & (HWSZ - 1);
    const size_t base = (size_t)b * (CC * HWSZ) + hw;      // channel-0 offset

    // Objectness mask quad (labela channel 0) — always needed.
    const float4 m4 = ld4(labela + base);

    float cell = 0.f;
    if (m4.x != 0.f || m4.y != 0.f || m4.z != 0.f || m4.w != 0.f) {
        float4 la[CC], pa[CC], lb[CC], pb[CC];
        la[0] = m4;
        #pragma unroll
        for (int c = 1; c < CC; ++c) la[c] = ld4(labela  + base + (size_t)c * HWSZ);
        #pragma unroll
        for (int c = 0; c < CC; ++c) pa[c] = ld4(pred_ab + base + (size_t)c * HWSZ);
        #pragma unroll
        for (int c = 0; c < CC; ++c) lb[c] = ld4(labelb  + base + (size_t)c * HWSZ);
        #pragma unroll
        for (int c = 0; c < CC; ++c) pb[c] = ld4(pred_ba + base + (size_t)c * HWSZ);

        float sx = 0.f, sy = 0.f, sz = 0.f, sw = 0.f;
        #pragma unroll
        for (int c = 0; c < CC; ++c) {
            float d;
            d = la[c].x - pa[c].x; sx += d * d;  d = lb[c].x - pb[c].x; sx += d * d;
            d = la[c].y - pa[c].y; sy += d * d;  d = lb[c].y - pb[c].y; sy += d * d;
            d = la[c].z - pa[c].z; sz += d * d;  d = lb[c].z - pb[c].z; sz += d * d;
            d = la[c].w - pa[c].w; sw += d * d;  d = lb[c].w - pb[c].w; sw += d * d;
        }
        cell = (m4.x != 0.f ? sx : 0.f)
             + (m4.y != 0.f ? sy : 0.f)
             + (m4.z != 0.f ? sz : 0.f)
             + (m4.w != 0.f ? sw : 0.f);
    }

    // wave(64) shuffle reduction
    #pragma unroll
    for (int off = 32; off > 0; off >>= 1)
        cell += __shfl_down(cell, off, 64);

    __shared__ float wsum[4];                 // 256 threads = 4 waves
    const int lane = threadIdx.x & 63;
    const int wid  = threadIdx.x >> 6;
    if (lane == 0) wsum[wid] = cell;
    __syncthreads();
    if (threadIdx.x == 0)
        ws[blockIdx.x] = wsum[0] + wsum[1] + wsum[2] + wsum[3];
}

// Kernel 2: reduce the 2048 partials -> out[0] (plain store; fully overwrites
// the harness's poison every call, so no memset is needed).
__global__ __launch_bounds__(256) void yolo_final_kernel(
    const float* __restrict__ ws,
    float* __restrict__ out)
{
    float s = 0.f;
    #pragma unroll
    for (int k = 0; k < NBLOCKS / 256; ++k)            // 8 strided loads/thread
        s += ws[threadIdx.x + k * 256];

    #pragma unroll
    for (int off = 32; off > 0; off >>= 1)
        s += __shfl_down(s, off, 64);

    __shared__ float wsum[4];
    const int lane = threadIdx.x & 63;
    const int wid  = threadIdx.x >> 6;
    if (lane == 0) wsum[wid] = s;
    __syncthreads();
    if (threadIdx.x == 0)
        out[0] = wsum[0] + wsum[1] + wsum[2] + wsum[3];
}

extern "C" void kernel_launch(void* const* d_in, const int* in_sizes, int n_in,
                              void* d_out, int out_size, void* d_ws, size_t ws_size,
                              hipStream_t stream) {
    const float* labela  = (const float*)d_in[0];
    const float* labelb  = (const float*)d_in[1];
    const float* pred_ab = (const float*)d_in[2];
    const float* pred_ba = (const float*)d_in[3];
    float* ws  = (float*)d_ws;    // 2048 floats = 8 KB of scratch
    float* out = (float*)d_out;

    yolo_partial_kernel<<<NBLOCKS, 256, 0, stream>>>(labela, labelb, pred_ab, pred_ba, ws);
    yolo_final_kernel<<<1, 256, 0, stream>>>(ws, out);
}